// Round 1
// baseline (1507.376 us; speedup 1.0000x reference)
//
#include <hip/hip_runtime.h>

typedef float v4f __attribute__((ext_vector_type(4)));

#define B_   64
#define CIN  64
#define CO   16
#define NN   307
#define LL   12
#define JT   (NN * LL)   // 3684
#define LHP  320         // padded lhat row stride (16B-aligned float4 rows)

// ---------------------------------------------------------------------------
// Kernel 0: repack w [o][i][k] -> wt [i][k][o] so the conv's weight reads are
// 16-float contiguous at a loop-uniform address (=> s_load_dwordx16).
// ---------------------------------------------------------------------------
__global__ void repack_w_kernel(const float* __restrict__ w, float* __restrict__ wt) {
    int t = blockIdx.x * 256 + threadIdx.x;
    if (t < CO * CIN * 3) {
        int o = t & 15;
        int k = (t >> 4) % 3;
        int i = t / 48;
        wt[i * 48 + k * 16 + o] = w[(o * CIN + i) * 3 + k];
    }
}

// ---------------------------------------------------------------------------
// Kernel 1: conv(1x3, pad 1) + bias + per-(b,n,l) channel-norm fold.
// One thread per (b,n,l); 16 channel accumulators in VGPRs; weights via
// uniform (scalar) loads from the repacked wt.
// Writes yhat[b][c][n][l] = y/max(||y||,eps) and lhat[b][c][n] (l==11 slice,
// padded row stride LHP for aligned float4 reads in kernel 2).
// ---------------------------------------------------------------------------
__global__ __launch_bounds__(256) void conv_norm_kernel(
    const float* __restrict__ x, const float* __restrict__ wt,
    const float* __restrict__ bias, float* __restrict__ yhat,
    float* __restrict__ lhat) {
    int tid = blockIdx.x * 256 + threadIdx.x;   // exactly B_*JT threads
    int b   = tid / JT;
    int rem = tid - b * JT;                     // n*12 + l
    int n   = rem / LL;
    int l   = rem - n * LL;

    const float* xp = x + (size_t)b * CIN * JT + rem;  // x[b][i][n][l] at xp + i*JT

    float acc[CO];
#pragma unroll
    for (int o = 0; o < CO; ++o) acc[o] = bias[o];

    const int   offm = (l > 0) ? -1 : 0;
    const int   offp = (l < LL - 1) ? 1 : 0;
    const float mm   = (l > 0) ? 1.f : 0.f;
    const float mp   = (l < LL - 1) ? 1.f : 0.f;

#pragma unroll 4
    for (int i = 0; i < CIN; ++i) {
        const float* xr = xp + i * JT;
        float xm = xr[offm] * mm;   // safe address (clamped), masked to 0
        float x0 = xr[0];
        float xq = xr[offp] * mp;
        const float* wr = wt + i * 48;   // uniform address -> scalar loads
#pragma unroll
        for (int o = 0; o < CO; ++o) {
            acc[o] += wr[o] * xm + wr[16 + o] * x0 + wr[32 + o] * xq;
        }
    }

    float ss = 0.f;
#pragma unroll
    for (int o = 0; o < CO; ++o) ss += acc[o] * acc[o];
    float inv = 1.f / fmaxf(sqrtf(ss), 1e-8f);

    float* yp = yhat + (size_t)b * CO * JT + rem;
#pragma unroll
    for (int o = 0; o < CO; ++o) yp[o * JT] = acc[o] * inv;

    if (l == LL - 1) {
        float* lp = lhat + (size_t)b * CO * LHP + n;
#pragma unroll
        for (int o = 0; o < CO; ++o) lp[o * LHP] = acc[o] * inv;
    }
}

// ---------------------------------------------------------------------------
// Kernel 2: out[b][i][jt] = sum_c lhat[b][c][i] * yhat[b][c][jt]
// Rank-16 GEMM, LDS-free. Block = 256 thr covers 64 i x 128 jt.
// Thread = 4 i x 8 jt (two float4 columns); lhat fragment (16 float4) lives
// in registers for the whole K loop; yhat columns stream from L1/L2.
// HBM-write-bound: nontemporal float4 stores.
// ---------------------------------------------------------------------------
__global__ __launch_bounds__(256, 3) void cos_kernel(
    const float* __restrict__ yhat, const float* __restrict__ lhat,
    float* __restrict__ out) {
    const int b   = blockIdx.z;
    const int i0  = blockIdx.y * 64;
    const int jt0 = blockIdx.x * 128;
    const int tx  = threadIdx.x & 15;
    const int ty  = threadIdx.x >> 4;
    const int ib  = i0 + ty * 4;
    const int jtA = jt0 + tx * 4;
    const int jtB = jtA + 64;
    const bool vA = (jtA < JT);   // JT % 4 == 0: whole-float4 validity
    const bool vB = (jtB < JT);

    const float* lp = lhat + (size_t)b * CO * LHP + ib;
    v4f lt[CO];
#pragma unroll
    for (int c = 0; c < CO; ++c) lt[c] = *(const v4f*)(lp + c * LHP);

    const float* yb = yhat + (size_t)b * CO * JT;

    v4f accA[4], accB[4];
#pragma unroll
    for (int r = 0; r < 4; ++r) { accA[r] = (v4f)0.f; accB[r] = (v4f)0.f; }

#pragma unroll
    for (int c = 0; c < CO; ++c) {
        v4f ya = vA ? *(const v4f*)(yb + c * JT + jtA) : (v4f)0.f;
        v4f yz = vB ? *(const v4f*)(yb + c * JT + jtB) : (v4f)0.f;
#pragma unroll
        for (int r = 0; r < 4; ++r) {
            float lv = lt[c][r];
            accA[r] += lv * ya;
            accB[r] += lv * yz;
        }
    }

#pragma unroll
    for (int r = 0; r < 4; ++r) {
        int i = ib + r;
        if (i < NN) {
            float* op = out + ((size_t)b * NN + i) * JT;
            if (vA) __builtin_nontemporal_store(accA[r], (v4f*)(op + jtA));
            if (vB) __builtin_nontemporal_store(accB[r], (v4f*)(op + jtB));
        }
    }
}

extern "C" void kernel_launch(void* const* d_in, const int* in_sizes, int n_in,
                              void* d_out, int out_size, void* d_ws, size_t ws_size,
                              hipStream_t stream) {
    const float* x    = (const float*)d_in[0];
    const float* w    = (const float*)d_in[1];
    const float* bias = (const float*)d_in[2];
    float* out = (float*)d_out;

    float* ws   = (float*)d_ws;
    float* yhat = ws;                                  // B_*CO*JT   = 3,772,416 f
    float* lhat = yhat + (size_t)B_ * CO * JT;         // B_*CO*LHP  =   327,680 f
    float* wt   = lhat + (size_t)B_ * CO * LHP;        // 3072 f     (~16.4 MB total)

    repack_w_kernel<<<(CO * CIN * 3 + 255) / 256, 256, 0, stream>>>(w, wt);

    conv_norm_kernel<<<(B_ * JT) / 256, 256, 0, stream>>>(x, wt, bias, yhat, lhat);

    dim3 g((JT + 127) / 128, (NN + 63) / 64, B_);
    cos_kernel<<<g, 256, 0, stream>>>(yhat, lhat, out);
}

// Round 2
// 408.542 us; speedup vs baseline: 3.6897x; 3.6897x over previous
//
#include <hip/hip_runtime.h>

typedef float v4f __attribute__((ext_vector_type(4)));

#define B_   64
#define CIN  64
#define CO   16
#define NN   307
#define LL   12
#define JT   (NN * LL)   // 3684
#define LHP  320         // padded lhat row stride (16B-aligned float4 rows)

// ---------------------------------------------------------------------------
// Kernel 0: repack w [o][i][k] -> wt [i][k][o] (loop-uniform 16-float rows).
// ---------------------------------------------------------------------------
__global__ void repack_w_kernel(const float* __restrict__ w, float* __restrict__ wt) {
    int t = blockIdx.x * 256 + threadIdx.x;
    if (t < CO * CIN * 3) {
        int o = t & 15;
        int k = (t >> 4) % 3;
        int i = t / 48;
        wt[i * 48 + k * 16 + o] = w[(o * CIN + i) * 3 + k];
    }
}

// ---------------------------------------------------------------------------
// Kernel 1: conv(1x3, pad 1) + bias + channel-norm fold.
// One thread per (b,n,l); weights via wave-uniform (scalar) loads.
// ---------------------------------------------------------------------------
__global__ __launch_bounds__(256) void conv_norm_kernel(
    const float* __restrict__ x, const float* __restrict__ wt,
    const float* __restrict__ bias, float* __restrict__ yhat,
    float* __restrict__ lhat) {
    int tid = blockIdx.x * 256 + threadIdx.x;   // exactly B_*JT threads
    int b   = tid / JT;
    int rem = tid - b * JT;                     // n*12 + l
    int n   = rem / LL;
    int l   = rem - n * LL;

    const float* xp = x + (size_t)b * CIN * JT + rem;

    float acc[CO];
#pragma unroll
    for (int o = 0; o < CO; ++o) acc[o] = bias[o];

    const int   offm = (l > 0) ? -1 : 0;
    const int   offp = (l < LL - 1) ? 1 : 0;
    const float mm   = (l > 0) ? 1.f : 0.f;
    const float mp   = (l < LL - 1) ? 1.f : 0.f;

#pragma unroll 4
    for (int i = 0; i < CIN; ++i) {
        const float* xr = xp + i * JT;
        float xm = xr[offm] * mm;
        float x0 = xr[0];
        float xq = xr[offp] * mp;
        const float* wr = wt + i * 48;   // wave-uniform address -> s_load
#pragma unroll
        for (int o = 0; o < CO; ++o) {
            acc[o] += wr[o] * xm + wr[16 + o] * x0 + wr[32 + o] * xq;
        }
    }

    float ss = 0.f;
#pragma unroll
    for (int o = 0; o < CO; ++o) ss += acc[o] * acc[o];
    float inv = 1.f / fmaxf(sqrtf(ss), 1e-8f);

    float* yp = yhat + (size_t)b * CO * JT + rem;
#pragma unroll
    for (int o = 0; o < CO; ++o) yp[o * JT] = acc[o] * inv;

    if (l == LL - 1) {
        float* lp = lhat + (size_t)b * CO * LHP + n;
#pragma unroll
        for (int o = 0; o < CO; ++o) lp[o * LHP] = acc[o] * inv;
    }
}

// ---------------------------------------------------------------------------
// Kernel 2: out[b][i][jt] = sum_c lhat[b][c][i] * yhat[b][c][jt]
// Rank-16 GEMM, LDS-free, WAVE-CONTIGUOUS stores:
//   wave = 4 output rows x 512 jt; each store instruction covers 64 lanes
//   x 16B = 1024B contiguous within ONE row -> L2 write-combines full lines.
// Plain (cached) stores — NO nontemporal: L2 must assemble full lines to
// avoid the RMW amplification seen in round 1.
// Block 256 thr = 4 waves -> 16 rows x 512 jt. lhat loads are wave-uniform.
// Grid: x = i-groups (fastest; 20 consecutive blocks share one yhat tile),
//       y = jt-groups, z = batch.
// ---------------------------------------------------------------------------
__global__ __launch_bounds__(256) void cos_kernel(
    const float* __restrict__ yhat, const float* __restrict__ lhat,
    float* __restrict__ out) {
    const int b    = blockIdx.z;
    const int i0   = blockIdx.x * 16;
    const int jt0  = blockIdx.y * 512;
    const int lane = threadIdx.x & 63;
    const int wv   = threadIdx.x >> 6;
    const int ib   = i0 + wv * 4;
    const int jtA  = jt0 + lane * 4;
    const int jtB  = jtA + 256;
    const bool vA  = (jtA < JT);   // JT % 4 == 0: whole-float4 validity
    const bool vB  = (jtB < JT);

    // lhat fragment: wave-uniform addresses -> scalar loads / broadcast
    const float* lp = lhat + (size_t)b * CO * LHP + ib;
    v4f lt[CO];
#pragma unroll
    for (int c = 0; c < CO; ++c) lt[c] = *(const v4f*)(lp + c * LHP);

    const float* yb = yhat + (size_t)b * CO * JT;

    v4f accA[4], accB[4];
#pragma unroll
    for (int r = 0; r < 4; ++r) { accA[r] = (v4f)0.f; accB[r] = (v4f)0.f; }

#pragma unroll
    for (int c = 0; c < CO; ++c) {
        v4f ya = vA ? *(const v4f*)(yb + c * JT + jtA) : (v4f)0.f;
        v4f yz = vB ? *(const v4f*)(yb + c * JT + jtB) : (v4f)0.f;
#pragma unroll
        for (int r = 0; r < 4; ++r) {
            float lv = lt[c][r];
            accA[r] += lv * ya;
            accB[r] += lv * yz;
        }
    }

#pragma unroll
    for (int r = 0; r < 4; ++r) {
        int i = ib + r;
        if (i < NN) {
            float* op = out + ((size_t)b * NN + i) * JT;
            if (vA) *(v4f*)(op + jtA) = accA[r];
            if (vB) *(v4f*)(op + jtB) = accB[r];
        }
    }
}

extern "C" void kernel_launch(void* const* d_in, const int* in_sizes, int n_in,
                              void* d_out, int out_size, void* d_ws, size_t ws_size,
                              hipStream_t stream) {
    const float* x    = (const float*)d_in[0];
    const float* w    = (const float*)d_in[1];
    const float* bias = (const float*)d_in[2];
    float* out = (float*)d_out;

    float* ws   = (float*)d_ws;
    float* yhat = ws;                                  // B_*CO*JT   = 3,772,416 f
    float* lhat = yhat + (size_t)B_ * CO * JT;         // B_*CO*LHP  =   327,680 f
    float* wt   = lhat + (size_t)B_ * CO * LHP;        // 3072 f     (~16.4 MB total)

    repack_w_kernel<<<(CO * CIN * 3 + 255) / 256, 256, 0, stream>>>(w, wt);

    conv_norm_kernel<<<(B_ * JT) / 256, 256, 0, stream>>>(x, wt, bias, yhat, lhat);

    // x = i-groups (ceil(307/16)=20), y = jt-groups (ceil(3684/512)=8), z = b
    dim3 g(20, 8, B_);
    cos_kernel<<<g, 256, 0, stream>>>(yhat, lhat, out);
}